// Round 5
// baseline (2795.977 us; speedup 1.0000x reference)
//
#include <hip/hip_runtime.h>
#include <hip/hip_bf16.h>
#include <cstdint>
#include <cstddef>

#define BB 256
#define TT 3000
#define II 40
#define HH 64
#define GG 256   // 4*H
#define XH 104   // II + HH concatenated
#define HALF 52  // per-thread slice

__device__ __forceinline__ float sigmoidf_(float x) {
  return __fdividef(1.0f, 1.0f + __expf(-x));
}
__device__ __forceinline__ float tanhf_(float x) {
  float t = __expf(2.0f * x);
  return 1.0f - __fdividef(2.0f, t + 1.0f);
}
__device__ __forceinline__ float bf16bits_lo(unsigned u) {
  return __uint_as_float(u << 16);
}
__device__ __forceinline__ float bf16bits_hi(unsigned u) {
  return __uint_as_float(u & 0xFFFF0000u);
}

// One block per (batch, direction). 512 threads = 8 waves.
// Gate row r = 32*w + (lane>>1); lane pair splits the 104-long dot in half:
// hs=0 -> [x(40); h(0..12)), hs=1 -> h[12..64). 52 weight f32 per thread in
// registers (13 float4) -- fits residency (vs 104 in R4, which spilled:
// VGPR_Count was 72 < 104). Halves combine via __shfl_xor(1).
// Per-wave xh LDS buffer: [0..40)=x (parity dbuf), [40..104)=h replica.
// One lgkmcnt-only barrier per step (gates exchange), no vmcnt drain.
__global__ __launch_bounds__(512, 2) void bilstm_kernel(
    const float* __restrict__ x,
    const float* __restrict__ W_ih_f, const float* __restrict__ W_hh_f,
    const float* __restrict__ b_ih_f, const float* __restrict__ b_hh_f,
    const float* __restrict__ W_ih_b, const float* __restrict__ W_hh_b,
    const float* __restrict__ b_ih_b, const float* __restrict__ b_hh_b,
    __hip_bfloat16* __restrict__ hcat) {
  const int tid  = threadIdx.x;
  const int lane = tid & 63;
  const int w    = tid >> 6;          // wave 0..7
  const int hs   = lane & 1;          // half-select within pair
  const int row  = (w << 5) | (lane >> 1);  // gate row 0..255
  const int b    = blockIdx.x & (BB - 1);
  const int dir  = blockIdx.x >> 8;

  const float* W_ih = dir ? W_ih_b : W_ih_f;
  const float* W_hh = dir ? W_hh_b : W_hh_f;
  const float* b_ih = dir ? b_ih_b : b_ih_f;
  const float* b_hh = dir ? b_hh_b : b_hh_f;

  __shared__ float xh[8][2][XH];   // per-wave: x (double-buffered) + h replica
  __shared__ float gsm[2][GG];     // activated gates, double-buffered

  // 52-float weight slice -> 13 float4 registers
  float4 wreg[13];
  if (hs == 0) {
    const float4* p = (const float4*)(W_ih + (size_t)row * II);
#pragma unroll
    for (int k = 0; k < 10; ++k) wreg[k] = p[k];
    const float4* q = (const float4*)(W_hh + (size_t)row * HH);
#pragma unroll
    for (int k = 0; k < 3; ++k) wreg[10 + k] = q[k];
  } else {
    const float4* q = (const float4*)(W_hh + (size_t)row * HH + 12);
#pragma unroll
    for (int k = 0; k < 13; ++k) wreg[k] = q[k];
  }
  const float bias = (hs == 0) ? (b_ih[row] + b_hh[row]) : 0.0f;

  float c = 0.0f;
  xh[w][0][II + lane] = 0.0f;  // h0 = 0 (parity-0 buffer), own-wave write

  const float* xb = x + (size_t)b * TT * II;
  __hip_bfloat16* hout = hcat + (size_t)b * TT * 128 + dir * HH;

#define TIDX(t_) (dir ? (TT - 1 - ((t_) < TT ? (t_) : TT - 1)) : ((t_) < TT ? (t_) : TT - 1))

  float xrA = 0.0f, xrB = 0.0f;
  if (lane < II) {
    xh[w][0][lane] = xb[(size_t)TIDX(0) * II + lane];
    xh[w][1][lane] = xb[(size_t)TIDX(1) * II + lane];
    xrA = xb[(size_t)TIDX(2) * II + lane];
    xrB = xb[(size_t)TIDX(3) * II + lane];
  }

#define STEP(T_, P_, XR_)                                                      \
  do {                                                                         \
    const int t_ = (T_);                                                       \
    /* half-dot: 13 float4 from own-wave LDS (wave-uniform per half) */        \
    const float4* xp = (const float4*)&xh[w][P_][hs * HALF];                   \
    float4 a;                                                                  \
    a.x = bias; a.y = 0.0f; a.z = 0.0f; a.w = 0.0f;                            \
    _Pragma("unroll")                                                          \
    for (int k = 0; k < 13; ++k) {                                             \
      float4 v = xp[k];                                                        \
      a.x = fmaf(wreg[k].x, v.x, a.x);                                         \
      a.y = fmaf(wreg[k].y, v.y, a.y);                                         \
      a.z = fmaf(wreg[k].z, v.z, a.z);                                         \
      a.w = fmaf(wreg[k].w, v.w, a.w);                                         \
    }                                                                          \
    float acc = (a.x + a.y) + (a.z + a.w);                                     \
    acc += __shfl_xor(acc, 1, 64); /* combine pair halves */                   \
    /* wave-uniform activation: waves 4,5 own rows 128..191 = g-gate */        \
    float act = ((w >> 1) == 2) ? tanhf_(acc) : sigmoidf_(acc);                \
    if (hs == 0) gsm[P_][row] = act;                                           \
    /* one barrier per step; lgkmcnt(0) only -- no vmcnt drain */              \
    asm volatile("s_waitcnt lgkmcnt(0)\n\ts_barrier" ::: "memory");            \
    /* cell update, redundant per wave (lane l owns cell l) */                 \
    float gi = gsm[P_][lane];                                                  \
    float gf = gsm[P_][HH + lane];                                             \
    float gg = gsm[P_][2 * HH + lane];                                         \
    float go = gsm[P_][3 * HH + lane];                                         \
    c = fmaf(gf, c, gi * gg);                                                  \
    float hv = go * tanhf_(c);                                                 \
    xh[w][1 - (P_)][II + lane] = hv; /* h_t consumed at t+1 (parity 1-P) */    \
    if (w == 0) hout[(size_t)TIDX(t_) * 128 + lane] = __float2bfloat16(hv);    \
    /* x pipeline: commit x_{t+2} into parity P, issue x_{t+4} */              \
    if (lane < II) {                                                           \
      xh[w][P_][lane] = XR_;                                                   \
      XR_ = xb[(size_t)TIDX(t_ + 4) * II + lane];                              \
    }                                                                          \
  } while (0)

  for (int t2 = 0; t2 < TT; t2 += 2) {
    STEP(t2, 0, xrA);
    STEP(t2 + 1, 1, xrB);
  }
#undef STEP
#undef TIDX
}

// MLP head: out[bt] = sigmoid(W2 . relu(W1 . h128 + b1) + b2), h in bf16.
__global__ __launch_bounds__(256, 2) void mlp_kernel(
    const unsigned* __restrict__ hcat,  // bf16 pairs packed in u32
    const float* __restrict__ W1, const float* __restrict__ b1,
    const float* __restrict__ W2, const float* __restrict__ b2,
    float* __restrict__ out) {
  __shared__ float4 w1s[64 * 32];  // 64 rows x 128 floats = 32 KiB
  __shared__ float  b1s[64];
  __shared__ float  w2s[64];
  __shared__ float  b2s;

  const int tid = threadIdx.x;
  const float4* w1g = (const float4*)W1;
  for (int i = tid; i < 64 * 32; i += 256) w1s[i] = w1g[i];
  if (tid < 64) { b1s[tid] = b1[tid]; w2s[tid] = W2[tid]; }
  if (tid == 0) b2s = b2[0];
  __syncthreads();

  const size_t bt = (size_t)blockIdx.x * 256 + tid;  // grid sized exactly
  float4 hreg[32];
  const uint4* hp = (const uint4*)(hcat + bt * 64);
#pragma unroll
  for (int k = 0; k < 16; ++k) {
    uint4 u = hp[k];
    hreg[2 * k].x     = bf16bits_lo(u.x);
    hreg[2 * k].y     = bf16bits_hi(u.x);
    hreg[2 * k].z     = bf16bits_lo(u.y);
    hreg[2 * k].w     = bf16bits_hi(u.y);
    hreg[2 * k + 1].x = bf16bits_lo(u.z);
    hreg[2 * k + 1].y = bf16bits_hi(u.z);
    hreg[2 * k + 1].z = bf16bits_lo(u.w);
    hreg[2 * k + 1].w = bf16bits_hi(u.w);
  }

  float acc2 = b2s;
  for (int o = 0; o < 64; ++o) {
    const float4* wv4 = &w1s[o * 32];
    float4 a; a.x = 0.0f; a.y = 0.0f; a.z = 0.0f; a.w = 0.0f;
#pragma unroll
    for (int k = 0; k < 32; ++k) {
      float4 wv = wv4[k];
      a.x = fmaf(wv.x, hreg[k].x, a.x);
      a.y = fmaf(wv.y, hreg[k].y, a.y);
      a.z = fmaf(wv.z, hreg[k].z, a.z);
      a.w = fmaf(wv.w, hreg[k].w, a.w);
    }
    float z = b1s[o] + (a.x + a.y) + (a.z + a.w);
    z = fmaxf(z, 0.0f);
    acc2 = fmaf(w2s[o], z, acc2);
  }
  out[bt] = sigmoidf_(acc2);
}

extern "C" void kernel_launch(void* const* d_in, const int* in_sizes, int n_in,
                              void* d_out, int out_size, void* d_ws, size_t ws_size,
                              hipStream_t stream) {
  const float* x      = (const float*)d_in[0];
  const float* W_ih_f = (const float*)d_in[1];
  const float* W_hh_f = (const float*)d_in[2];
  const float* b_ih_f = (const float*)d_in[3];
  const float* b_hh_f = (const float*)d_in[4];
  const float* W_ih_b = (const float*)d_in[5];
  const float* W_hh_b = (const float*)d_in[6];
  const float* b_ih_b = (const float*)d_in[7];
  const float* b_hh_b = (const float*)d_in[8];
  const float* W1     = (const float*)d_in[9];
  const float* b1     = (const float*)d_in[10];
  const float* W2     = (const float*)d_in[11];
  const float* b2     = (const float*)d_in[12];
  float* out = (float*)d_out;
  __hip_bfloat16* hcat = (__hip_bfloat16*)d_ws;  // (B, T, 128) bf16 = 196.6 MB

  bilstm_kernel<<<dim3(2 * BB), dim3(512), 0, stream>>>(
      x, W_ih_f, W_hh_f, b_ih_f, b_hh_f, W_ih_b, W_hh_b, b_ih_b, b_hh_b, hcat);

  mlp_kernel<<<dim3(3000), dim3(256), 0, stream>>>((const unsigned*)hcat,
                                                   W1, b1, W2, b2, out);
}